// Round 2
// baseline (733.780 us; speedup 1.0000x reference)
//
#include <hip/hip_runtime.h>

#define Bb 2
#define Ss 2048
#define Dd 1024
#define Hh 16
#define HD 64
#define Mm (Bb*Ss)   // 4096

typedef __bf16 bf16;
typedef __bf16 bf16x8 __attribute__((ext_vector_type(8)));
typedef float f32x4 __attribute__((ext_vector_type(4)));

// async global->LDS, 16B per lane; dest must be wave-uniform base + lane*16 (linear)
__device__ __forceinline__ void gload_lds16(const bf16* g, bf16* l) {
    __builtin_amdgcn_global_load_lds(
        (const __attribute__((address_space(1))) unsigned int*)g,
        (__attribute__((address_space(3))) unsigned int*)l,
        16, 0, 0);
}

// ---------------- prep: fp32 -> bf16 cast ----------------
__global__ void cvt_f32_bf16(const float* __restrict__ in, bf16* __restrict__ out, int n4) {
    int i = blockIdx.x * blockDim.x + threadIdx.x;
    if (i < n4) {
        float4 v = *(const float4*)(in + i * 4);
        out[i*4+0] = (bf16)v.x; out[i*4+1] = (bf16)v.y;
        out[i*4+2] = (bf16)v.z; out[i*4+3] = (bf16)v.w;
    }
}

// ---------------- prep: W [K,N] fp32 -> Wt [N,K] bf16 ----------------
__global__ void wtrans(const float* __restrict__ W0, const float* __restrict__ W1,
                       const float* __restrict__ W2, const float* __restrict__ W3,
                       bf16* __restrict__ O0, bf16* __restrict__ O1,
                       bf16* __restrict__ O2, bf16* __restrict__ O3) {
    const float* W = (blockIdx.z == 0) ? W0 : (blockIdx.z == 1) ? W1 : (blockIdx.z == 2) ? W2 : W3;
    bf16* O = (blockIdx.z == 0) ? O0 : (blockIdx.z == 1) ? O1 : (blockIdx.z == 2) ? O2 : O3;
    __shared__ bf16 t[64][65];
    int k0 = blockIdx.x * 64, n0 = blockIdx.y * 64;
    for (int c = threadIdx.x; c < 4096; c += 256) {
        int r = c >> 6, cc = c & 63;
        t[r][cc] = (bf16)W[(k0 + r) * Dd + n0 + cc];
    }
    __syncthreads();
    for (int c = threadIdx.x; c < 4096; c += 256) {
        int r = c >> 6, cc = c & 63;
        O[(n0 + r) * Dd + k0 + cc] = t[cc][r];
    }
}

// ---------------- GEMM: C[M,N] = A[M,K] * Bt[N,K]^T + bias ----------------
// BM x 128 tile, BK=32, 4 waves. Double-buffered LDS, stage(t+1) issued before
// compute(t), ONE barrier per K-step (T3-minimum pipeline).
// mode 0: out o0[m*1024+n] (+b0). mode 1: fused QKV, Bt = [WqT;WkT;WvT] (3072x1024),
//         n selects {o0,o1,o2}/{b0,b1,b2}, output in [B,H,S,HD] split-head layout.
template<int BM>
__global__ __launch_bounds__(256, (BM == 64) ? 4 : 3)
void gemm_bt(const bf16* __restrict__ A, const bf16* __restrict__ Bt,
             const float* __restrict__ b0, const float* __restrict__ b1, const float* __restrict__ b2,
             bf16* __restrict__ o0, bf16* __restrict__ o1, bf16* __restrict__ o2, int mode) {
    const int K = 1024;
    constexpr int MI = BM / 32;   // 16-row acc tiles per wave
    __shared__ __align__(16) bf16 As[2][BM * 32];
    __shared__ __align__(16) bf16 Bs[2][128 * 32];
    int tid = threadIdx.x;
    int wave = tid >> 6, lane = tid & 63;
    int lane15 = lane & 15, quad = lane >> 4;
    int wm = (wave >> 1) * (BM / 2), wn = (wave & 1) * 64;
    int m0 = blockIdx.x * BM, n0 = blockIdx.y * 128;
    // staging map: lane covers (row = wave*16 + lane>>2, cols (lane&3)*8..+8)
    int lrow = lane >> 2, lcol = (lane & 3) * 8;
    const bf16* Ag = &A[(size_t)(m0 + wave * 16 + lrow) * K + lcol];
    const bf16* Bg = &Bt[(size_t)(n0 + wave * 16 + lrow) * K + lcol];

    f32x4 acc[MI][4] = {};

#define STAGE(buf, kt) do { \
        bf16* Asw = &As[buf][wave * 16 * 32]; \
        bf16* Bsw = &Bs[buf][wave * 16 * 32]; \
        gload_lds16(Ag + (kt), Asw); \
        if constexpr (BM == 128) gload_lds16(Ag + 64 * K + (kt), Asw + 64 * 32); \
        gload_lds16(Bg + (kt), Bsw); \
        gload_lds16(Bg + 64 * K + (kt), Bsw + 64 * 32); \
    } while (0)

    STAGE(0, 0);
    __syncthreads();            // drain prologue stage
    int cur = 0;
    for (int kt = 0; kt < K; kt += 32) {
        if (kt + 32 < K) STAGE(cur ^ 1, kt + 32);   // async, in flight during compute
        bf16x8 af[MI], bfr[4];
#pragma unroll
        for (int i = 0; i < MI; i++) af[i] = *(const bf16x8*)(&As[cur][(wm + i * 16 + lane15) * 32 + quad * 8]);
#pragma unroll
        for (int j = 0; j < 4; j++) bfr[j] = *(const bf16x8*)(&Bs[cur][(wn + j * 16 + lane15) * 32 + quad * 8]);
#pragma unroll
        for (int i = 0; i < MI; i++)
#pragma unroll
            for (int j = 0; j < 4; j++)
                acc[i][j] = __builtin_amdgcn_mfma_f32_16x16x32_bf16(af[i], bfr[j], acc[i][j], 0, 0, 0);
        __syncthreads();        // drains stage(t+1) writes + guards buffer reuse
        cur ^= 1;
    }
#undef STAGE

#pragma unroll
    for (int i = 0; i < MI; i++) {
        int mbase = m0 + wm + i * 16 + quad * 4;
#pragma unroll
        for (int j = 0; j < 4; j++) {
            int n = n0 + wn + j * 16 + lane15;
            if (mode == 0) {
                float bv = b0[n];
#pragma unroll
                for (int r = 0; r < 4; r++)
                    o0[(size_t)(mbase + r) * 1024 + n] = (bf16)(acc[i][j][r] + bv);
            } else {
                int which = n >> 10, nn = n & 1023;
                const float* bp = (which == 0) ? b0 : (which == 1) ? b1 : b2;
                bf16* op = (which == 0) ? o0 : (which == 1) ? o1 : o2;
                float bv = bp[nn];
                int hh = nn >> 6, hd = nn & 63;
#pragma unroll
                for (int r = 0; r < 4; r++) {
                    int m = mbase + r;
                    int bb = m >> 11, s = m & 2047;
                    op[(((size_t)(bb * Hh + hh) * Ss + s) * HD) + hd] = (bf16)(acc[i][j][r] + bv);
                }
            }
        }
    }
}

// ---------------- flash attention ----------------
// grid: (qt=32, h=16, b=2), 256 threads (4 waves). Wave w owns q rows [qt*64+w*16, +16).
// v2 (T14 async-stage): K/V for tile t+1 prefetched to REGISTERS at loop top,
// written to LDS after the post-PV barrier -> global latency hides under compute.
// alibi/mask: direct global->register (L2-shared across b=0/1), issued BEFORE the
// K/V prefetch so the compiler's alibi vmcnt-wait leaves K/V loads in flight.
// QPs (Q and P) is wave-private -> P roundtrip needs only s_waitcnt lgkmcnt(0),
// no barrier. 2 barriers/tile. LDS 24KB -> 4 blocks/CU (VGPR-capped).
__global__ __launch_bounds__(256, 4)
void attn_kernel(const bf16* __restrict__ Q, const bf16* __restrict__ Kk, const bf16* __restrict__ V,
                 const float* __restrict__ alibi, const float* __restrict__ mask,
                 bf16* __restrict__ outattn) {
    int qt = blockIdx.x, h = blockIdx.y, b = blockIdx.z;
    __shared__ __align__(16) bf16 Ks[64 * 64];
    __shared__ __align__(16) bf16 Vts[64 * 64];
    __shared__ __align__(16) bf16 QPs[64 * 64];
    int tid = threadIdx.x, wave = tid >> 6, lane = tid & 63;
    int lane15 = lane & 15, quad = lane >> 4;

    const bf16* Qbase = Q + ((size_t)(b * Hh + h) * Ss + qt * 64) * HD;
    const bf16* Kbase = Kk + (size_t)(b * Hh + h) * Ss * HD;
    const bf16* Vbase = V + (size_t)(b * Hh + h) * Ss * HD;
    const float* alibi_q = alibi + ((size_t)h * Ss + qt * 64 + wave * 16 + quad * 4) * Ss;
    const float* mask_base = mask + (size_t)b * Ss;

    // staging coords: thread covers rows sr and sr+32 at cols soff..soff+8
    int sr = tid >> 3, soff = (tid & 7) * 8;

    // ---- prologue: Q stage + K/V tile0 direct stage ----
    for (int c = tid; c < 512; c += 256) {
        int r = c >> 3, off = (c & 7) * 8;
        *(bf16x8*)(&QPs[r * 64 + (off ^ ((r & 7) * 8))]) = *(const bf16x8*)(&Qbase[r * HD + off]);
    }
    {
        bf16x8 k0 = *(const bf16x8*)(&Kbase[(size_t)sr * HD + soff]);
        bf16x8 k1 = *(const bf16x8*)(&Kbase[(size_t)(sr + 32) * HD + soff]);
        bf16x8 v0 = *(const bf16x8*)(&Vbase[(size_t)sr * HD + soff]);
        bf16x8 v1 = *(const bf16x8*)(&Vbase[(size_t)(sr + 32) * HD + soff]);
        *(bf16x8*)(&Ks[sr * 64 + (soff ^ ((sr & 7) * 8))]) = k0;
        *(bf16x8*)(&Ks[(sr + 32) * 64 + (soff ^ (((sr + 32) & 7) * 8))]) = k1;
#pragma unroll
        for (int e = 0; e < 8; e++) {
            int d = soff + e;
            int vs = (((d & 7) ^ ((d >> 3) & 7)) * 8);
            Vts[d * 64 + (sr ^ vs)] = v0[e];
            Vts[d * 64 + ((sr + 32) ^ vs)] = v1[e];
        }
    }
    __syncthreads();

    int qrow = wave * 16 + lane15;
    bf16x8 qf0 = *(const bf16x8*)(&QPs[qrow * 64 + ((quad * 8) ^ ((qrow & 7) * 8))]);
    bf16x8 qf1 = *(const bf16x8*)(&QPs[qrow * 64 + ((32 + quad * 8) ^ ((qrow & 7) * 8))]);

    float m_i[4], l_i[4];
    f32x4 O[4] = {};
#pragma unroll
    for (int r = 0; r < 4; r++) { m_i[r] = -1e30f; l_i[r] = 0.f; }

    const float scale = 0.125f;  // HD^-0.5

    for (int kt = 0; kt < Ss; kt += 64) {
        bool hn = (kt + 64) < Ss;
        // (A) alibi + mask for THIS tile -> registers (issued first = oldest vmcnt)
        float al[4][4], mk[4];
#pragma unroll
        for (int j = 0; j < 4; j++) {
#pragma unroll
            for (int r = 0; r < 4; r++)
                al[j][r] = alibi_q[(size_t)r * Ss + kt + j * 16 + lane15];
            mk[j] = mask_base[kt + j * 16 + lane15];
        }
        // (B) K/V prefetch for NEXT tile -> registers (stays in flight past alibi wait)
        bf16x8 kn0, kn1, vn0, vn1;
        if (hn) {
            const bf16* Kn = Kbase + (size_t)(kt + 64) * HD;
            const bf16* Vn = Vbase + (size_t)(kt + 64) * HD;
            kn0 = *(const bf16x8*)(&Kn[(size_t)sr * HD + soff]);
            kn1 = *(const bf16x8*)(&Kn[(size_t)(sr + 32) * HD + soff]);
            vn0 = *(const bf16x8*)(&Vn[(size_t)sr * HD + soff]);
            vn1 = *(const bf16x8*)(&Vn[(size_t)(sr + 32) * HD + soff]);
        }

        // (C) QK^T from LDS
        f32x4 sc[4];
        f32x4 z = {0.f, 0.f, 0.f, 0.f};
#pragma unroll
        for (int j = 0; j < 4; j++) {
            int krow = j * 16 + lane15;
            bf16x8 kf0 = *(const bf16x8*)(&Ks[krow * 64 + ((quad * 8) ^ ((krow & 7) * 8))]);
            bf16x8 kf1 = *(const bf16x8*)(&Ks[krow * 64 + ((32 + quad * 8) ^ ((krow & 7) * 8))]);
            f32x4 s = __builtin_amdgcn_mfma_f32_16x16x32_bf16(qf0, kf0, z, 0, 0, 0);
            s = __builtin_amdgcn_mfma_f32_16x16x32_bf16(qf1, kf1, s, 0, 0, 0);
            sc[j] = s;
        }
        // (D) scores (compiler waits alibi/mask here with K/V still outstanding)
#pragma unroll
        for (int j = 0; j < 4; j++)
#pragma unroll
            for (int r = 0; r < 4; r++)
                sc[j][r] = sc[j][r] * scale + al[j][r] + mk[j];
        // (E) online softmax
        float alpha[4];
#pragma unroll
        for (int r = 0; r < 4; r++) {
            float v = fmaxf(fmaxf(sc[0][r], sc[1][r]), fmaxf(sc[2][r], sc[3][r]));
#pragma unroll
            for (int d = 1; d < 16; d <<= 1) v = fmaxf(v, __shfl_xor(v, d, 64));
            float mnew = fmaxf(m_i[r], v);
            alpha[r] = __expf(m_i[r] - mnew);
            m_i[r] = mnew;
        }
        float rs[4] = {0.f, 0.f, 0.f, 0.f};
#pragma unroll
        for (int j = 0; j < 4; j++)
#pragma unroll
            for (int r = 0; r < 4; r++) {
                float p = __expf(sc[j][r] - m_i[r]);
                sc[j][r] = p;
                rs[r] += p;
            }
#pragma unroll
        for (int r = 0; r < 4; r++) {
            float v = rs[r];
#pragma unroll
            for (int d = 1; d < 16; d <<= 1) v += __shfl_xor(v, d, 64);
            l_i[r] = l_i[r] * alpha[r] + v;
        }
        // (F) P -> LDS (QPs rows are wave-private: no barrier, just LDS drain)
#pragma unroll
        for (int j = 0; j < 4; j++)
#pragma unroll
            for (int r = 0; r < 4; r++) {
                int row = wave * 16 + quad * 4 + r;
                QPs[row * 64 + ((j * 16 + lane15) ^ ((row & 7) * 8))] = (bf16)sc[j][r];
            }
        asm volatile("s_waitcnt lgkmcnt(0)" ::: "memory");
        int prow = wave * 16 + lane15;
        bf16x8 pf0 = *(const bf16x8*)(&QPs[prow * 64 + ((quad * 8) ^ ((prow & 7) * 8))]);
        bf16x8 pf1 = *(const bf16x8*)(&QPs[prow * 64 + ((32 + quad * 8) ^ ((prow & 7) * 8))]);
        // (G) PV
#pragma unroll
        for (int jd = 0; jd < 4; jd++) {
            int vrow = jd * 16 + lane15;
            int vs = (((vrow & 7) ^ ((vrow >> 3) & 7)) * 8);
#pragma unroll
            for (int r = 0; r < 4; r++) O[jd][r] *= alpha[r];
            bf16x8 vf0 = *(const bf16x8*)(&Vts[vrow * 64 + ((quad * 8) ^ vs)]);
            bf16x8 vf1 = *(const bf16x8*)(&Vts[vrow * 64 + ((32 + quad * 8) ^ vs)]);
            O[jd] = __builtin_amdgcn_mfma_f32_16x16x32_bf16(pf0, vf0, O[jd], 0, 0, 0);
            O[jd] = __builtin_amdgcn_mfma_f32_16x16x32_bf16(pf1, vf1, O[jd], 0, 0, 0);
        }
        // (H) all waves done reading Ks/Vts
        __syncthreads();
        // (I) write prefetched K/V tile t+1 (vmcnt wait lands here)
        if (hn) {
            *(bf16x8*)(&Ks[sr * 64 + (soff ^ ((sr & 7) * 8))]) = kn0;
            *(bf16x8*)(&Ks[(sr + 32) * 64 + (soff ^ (((sr + 32) & 7) * 8))]) = kn1;
#pragma unroll
            for (int e = 0; e < 8; e++) {
                int d = soff + e;
                int vs = (((d & 7) ^ ((d >> 3) & 7)) * 8);
                Vts[d * 64 + (sr ^ vs)] = vn0[e];
                Vts[d * 64 + ((sr + 32) ^ vs)] = vn1[e];
            }
        }
        // (J) staging visible to all
        __syncthreads();
    }

#pragma unroll
    for (int jd = 0; jd < 4; jd++) {
        int d = jd * 16 + lane15;
#pragma unroll
        for (int r = 0; r < 4; r++) {
            int qg = qt * 64 + wave * 16 + quad * 4 + r;
            float v = O[jd][r] / l_i[r];
            outattn[(((size_t)b * Ss + qg) * Hh + h) * HD + d] = (bf16)v;
        }
    }
}

// ---------------- residual + layernorm ----------------
__global__ void ln_kernel(const float* __restrict__ hidden, const bf16* __restrict__ Y,
                          const float* __restrict__ gamma, const float* __restrict__ beta,
                          float* __restrict__ out) {
    int row = blockIdx.x;
    int tid = threadIdx.x, wave = tid >> 6, lane = tid & 63;
    float x[4];
    float s = 0.f, q = 0.f;
#pragma unroll
    for (int e = 0; e < 4; e++) {
        int col = e * 256 + tid;
        x[e] = hidden[(size_t)row * Dd + col] + (float)Y[(size_t)row * Dd + col];
        s += x[e];
        q += x[e] * x[e];
    }
#pragma unroll
    for (int d = 1; d < 64; d <<= 1) { s += __shfl_xor(s, d, 64); q += __shfl_xor(q, d, 64); }
    __shared__ float sm[4], sq[4];
    if (lane == 0) { sm[wave] = s; sq[wave] = q; }
    __syncthreads();
    float tot = sm[0] + sm[1] + sm[2] + sm[3];
    float totq = sq[0] + sq[1] + sq[2] + sq[3];
    float mu = tot * (1.f / 1024.f);
    float var = totq * (1.f / 1024.f) - mu * mu;
    float rstd = rsqrtf(var + 1e-12f);
#pragma unroll
    for (int e = 0; e < 4; e++) {
        int col = e * 256 + tid;
        out[(size_t)row * Dd + col] = (x[e] - mu) * rstd * gamma[col] + beta[col];
    }
}

// ---------------- launch ----------------
extern "C" void kernel_launch(void* const* d_in, const int* in_sizes, int n_in,
                              void* d_out, int out_size, void* d_ws, size_t ws_size,
                              hipStream_t stream) {
    const float* hidden = (const float*)d_in[0];
    const float* amask  = (const float*)d_in[1];
    const float* alibi  = (const float*)d_in[2];
    const float* Wq = (const float*)d_in[3];
    const float* bq = (const float*)d_in[4];
    const float* Wk = (const float*)d_in[5];
    const float* bk = (const float*)d_in[6];
    const float* Wv = (const float*)d_in[7];
    const float* bv = (const float*)d_in[8];
    const float* Wo = (const float*)d_in[9];
    const float* bo = (const float*)d_in[10];
    const float* ln_g = (const float*)d_in[11];
    const float* ln_b = (const float*)d_in[12];
    float* out = (float*)d_out;

    char* w = (char*)d_ws;
    bf16* Xb   = (bf16*)(w);                       // 4096x1024      8,388,608 B
    bf16* WqT  = (bf16*)(w + 8388608);             // [WqT;WkT;WvT] contiguous 3072x1024
    bf16* WkT  = (bf16*)(w + 10485760);
    bf16* WvT  = (bf16*)(w + 12582912);
    bf16* WoT  = (bf16*)(w + 14680064);
    bf16* Qw   = (bf16*)(w + 16777216);            // [B,H,S,HD]     8,388,608 B
    bf16* Kw   = (bf16*)(w + 25165824);
    bf16* Vw   = (bf16*)(w + 33554432);
    bf16* Attn = (bf16*)(w + 41943040);            // [B,S,H,HD] = [4096,1024]
    bf16* Yw   = (bf16*)(w + 50331648);            // [4096,1024]

    cvt_f32_bf16<<<4096, 256, 0, stream>>>(hidden, Xb, Mm * Dd / 4);
    wtrans<<<dim3(16, 16, 4), 256, 0, stream>>>(Wq, Wk, Wv, Wo, WqT, WkT, WvT, WoT);

    // fused QKV GEMM: Bt = [WqT;WkT;WvT] (3072 rows), grid 32x24 = 768 blocks = 3/CU
    gemm_bt<128><<<dim3(32, 24), 256, 0, stream>>>(Xb, WqT, bq, bk, bv, Qw, Kw, Vw, 1);

    attn_kernel<<<dim3(32, 16, 2), 256, 0, stream>>>(Qw, Kw, Vw, alibi, amask, Attn);

    // Wo GEMM: BM=64 -> grid 64x8 = 512 blocks = 2/CU
    gemm_bt<64><<<dim3(64, 8), 256, 0, stream>>>(Attn, WoT, bo, nullptr, nullptr, Yw, nullptr, nullptr, 0);

    ln_kernel<<<4096, 256, 0, stream>>>(hidden, Yw, ln_g, ln_b, out);
}

// Round 3
// 567.659 us; speedup vs baseline: 1.2926x; 1.2926x over previous
//
#include <hip/hip_runtime.h>

#define Bb 2
#define Ss 2048
#define Dd 1024
#define Hh 16
#define HD 64
#define Mm (Bb*Ss)   // 4096
#define KVB 64

typedef __bf16 bf16;
typedef __bf16 bf16x8 __attribute__((ext_vector_type(8)));
typedef float f32x4 __attribute__((ext_vector_type(4)));

// async global->LDS, 16B per lane; LDS dest must be wave-uniform base (+lane*16 implicit)
#define GL(gp, lp) __builtin_amdgcn_global_load_lds( \
        (const __attribute__((address_space(1))) unsigned int*)(gp), \
        (__attribute__((address_space(3))) unsigned int*)(lp), 16, 0, 0)

// ---------------- prep: fp32 -> bf16 cast ----------------
__global__ void cvt_f32_bf16(const float* __restrict__ in, bf16* __restrict__ out, int n4) {
    int i = blockIdx.x * blockDim.x + threadIdx.x;
    if (i < n4) {
        float4 v = *(const float4*)(in + i * 4);
        out[i*4+0] = (bf16)v.x; out[i*4+1] = (bf16)v.y;
        out[i*4+2] = (bf16)v.z; out[i*4+3] = (bf16)v.w;
    }
}

// ---------------- prep: W [K,N] fp32 -> Wt [N,K] bf16 ----------------
__global__ void wtrans(const float* __restrict__ W0, const float* __restrict__ W1,
                       const float* __restrict__ W2, const float* __restrict__ W3,
                       bf16* __restrict__ O0, bf16* __restrict__ O1,
                       bf16* __restrict__ O2, bf16* __restrict__ O3) {
    const float* W = (blockIdx.z == 0) ? W0 : (blockIdx.z == 1) ? W1 : (blockIdx.z == 2) ? W2 : W3;
    bf16* O = (blockIdx.z == 0) ? O0 : (blockIdx.z == 1) ? O1 : (blockIdx.z == 2) ? O2 : O3;
    __shared__ bf16 t[64][65];
    int k0 = blockIdx.x * 64, n0 = blockIdx.y * 64;
    for (int c = threadIdx.x; c < 4096; c += 256) {
        int r = c >> 6, cc = c & 63;
        t[r][cc] = (bf16)W[(k0 + r) * Dd + n0 + cc];
    }
    __syncthreads();
    for (int c = threadIdx.x; c < 4096; c += 256) {
        int r = c >> 6, cc = c & 63;
        O[(n0 + r) * Dd + k0 + cc] = t[cc][r];
    }
}

// ---------------- prep: V [BH,S,HD] -> Vt [BH,HD,S] ----------------
__global__ void vtrans(const bf16* __restrict__ in, bf16* __restrict__ out) {
    __shared__ bf16 t[64][72];
    int s0 = blockIdx.x * 64, bh = blockIdx.y;
    int tid = threadIdx.x;
    int r = tid >> 3, c = (tid & 7) * 8;
    const bf16* ib = in + ((size_t)bh * Ss + s0) * HD;
    bf16x8 v0 = *(const bf16x8*)(&ib[(size_t)r * HD + c]);
    bf16x8 v1 = *(const bf16x8*)(&ib[(size_t)(r + 32) * HD + c]);
    *(bf16x8*)(&t[r][c]) = v0;
    *(bf16x8*)(&t[r + 32][c]) = v1;
    __syncthreads();
    int d0 = tid >> 3, d1 = d0 + 32, sc2 = (tid & 7) * 8;
    bf16x8 o0, o1;
#pragma unroll
    for (int e = 0; e < 8; e++) { o0[e] = t[sc2 + e][d0]; o1[e] = t[sc2 + e][d1]; }
    *(bf16x8*)(&out[((size_t)(bh * HD + d0)) * Ss + s0 + sc2]) = o0;
    *(bf16x8*)(&out[((size_t)(bh * HD + d1)) * Ss + s0 + sc2]) = o1;
}

// ---------------- GEMM: C[M,N] = A[M,K] * Bt[N,K]^T + bias ----------------
// BM x 128 tile, BK=32, 4 waves. Double-buffered LDS, stage(t+1) before compute(t),
// one barrier per K-step.
template<int BM>
__global__ __launch_bounds__(256, (BM == 64) ? 4 : 3)
void gemm_bt(const bf16* __restrict__ A, const bf16* __restrict__ Bt,
             const float* __restrict__ b0, const float* __restrict__ b1, const float* __restrict__ b2,
             bf16* __restrict__ o0, bf16* __restrict__ o1, bf16* __restrict__ o2, int mode) {
    const int K = 1024;
    constexpr int MI = BM / 32;
    __shared__ __align__(16) bf16 As[2][BM * 32];
    __shared__ __align__(16) bf16 Bs[2][128 * 32];
    int tid = threadIdx.x;
    int wave = tid >> 6, lane = tid & 63;
    int lane15 = lane & 15, quad = lane >> 4;
    int wm = (wave >> 1) * (BM / 2), wn = (wave & 1) * 64;
    int m0 = blockIdx.x * BM, n0 = blockIdx.y * 128;
    int lrow = lane >> 2, lcol = (lane & 3) * 8;
    const bf16* Ag = &A[(size_t)(m0 + wave * 16 + lrow) * K + lcol];
    const bf16* Bg = &Bt[(size_t)(n0 + wave * 16 + lrow) * K + lcol];

    f32x4 acc[MI][4] = {};

#define STAGE(buf, kt) do { \
        bf16* Asw = &As[buf][wave * 16 * 32]; \
        bf16* Bsw = &Bs[buf][wave * 16 * 32]; \
        GL(Ag + (kt), Asw); \
        if constexpr (BM == 128) GL(Ag + 64 * K + (kt), Asw + 64 * 32); \
        GL(Bg + (kt), Bsw); \
        GL(Bg + 64 * K + (kt), Bsw + 64 * 32); \
    } while (0)

    STAGE(0, 0);
    __syncthreads();
    int cur = 0;
    for (int kt = 0; kt < K; kt += 32) {
        if (kt + 32 < K) STAGE(cur ^ 1, kt + 32);
        bf16x8 af[MI], bfr[4];
#pragma unroll
        for (int i = 0; i < MI; i++) af[i] = *(const bf16x8*)(&As[cur][(wm + i * 16 + lane15) * 32 + quad * 8]);
#pragma unroll
        for (int j = 0; j < 4; j++) bfr[j] = *(const bf16x8*)(&Bs[cur][(wn + j * 16 + lane15) * 32 + quad * 8]);
#pragma unroll
        for (int i = 0; i < MI; i++)
#pragma unroll
            for (int j = 0; j < 4; j++)
                acc[i][j] = __builtin_amdgcn_mfma_f32_16x16x32_bf16(af[i], bfr[j], acc[i][j], 0, 0, 0);
        __syncthreads();
        cur ^= 1;
    }
#undef STAGE

#pragma unroll
    for (int i = 0; i < MI; i++) {
        int mbase = m0 + wm + i * 16 + quad * 4;
#pragma unroll
        for (int j = 0; j < 4; j++) {
            int n = n0 + wn + j * 16 + lane15;
            if (mode == 0) {
                float bv = b0[n];
#pragma unroll
                for (int r = 0; r < 4; r++)
                    o0[(size_t)(mbase + r) * 1024 + n] = (bf16)(acc[i][j][r] + bv);
            } else {
                int which = n >> 10, nn = n & 1023;
                const float* bp = (which == 0) ? b0 : (which == 1) ? b1 : b2;
                bf16* op = (which == 0) ? o0 : (which == 1) ? o1 : o2;
                float bv = bp[nn];
                int hh = nn >> 6, hd = nn & 63;
#pragma unroll
                for (int r = 0; r < 4; r++) {
                    int m = mbase + r;
                    int bb = m >> 11, s = m & 2047;
                    op[(((size_t)(bb * Hh + hh) * Ss + s) * HD) + hd] = (bf16)(acc[i][j][r] + bv);
                }
            }
        }
    }
}

// ---------------- flash attention ----------------
// 1024 blocks 1-D, 256 threads (4 waves). Twin decode: b=(id>>3)&1, so b=0/b=1 blocks
// with the same (qt,h) are 8 apart -> same XCD, launched adjacently -> alibi L2/L3 reuse.
// ALL in-loop memory traffic is LDS; global streams (K, Vt, alibi fp32) are staged by
// global_load_lds with pre-swizzled GLOBAL source addresses (linear LDS dest), double-
// buffered, issued one tile ahead. LDS = 80 KB -> 2 blocks/CU. No VGPR prefetch -> no spill.
__global__ __launch_bounds__(256, 2)
void attn_kernel(const bf16* __restrict__ Q, const bf16* __restrict__ Kk, const bf16* __restrict__ Vt,
                 const float* __restrict__ alibi, const float* __restrict__ mask,
                 bf16* __restrict__ outattn) {
    int hwid = blockIdx.x;
    int b = (hwid >> 3) & 1;
    int pid = ((hwid >> 4) << 3) | (hwid & 7);
    int qt = pid & 31, h = pid >> 5;

    __shared__ __align__(16) bf16 Ks[2][64 * 64];
    __shared__ __align__(16) bf16 Vts[2][64 * 64];
    __shared__ __align__(16) float Als[2][64 * 64];
    __shared__ __align__(16) bf16 QPs[64 * 64];
    __shared__ __align__(16) float Ms[2048];

    int tid = threadIdx.x, wave = tid >> 6, lane = tid & 63;
    int lane15 = lane & 15, quad = lane >> 4;

    const bf16* Qbase = Q + ((size_t)(b * Hh + h) * Ss + qt * 64) * HD;
    const bf16* Kbase = Kk + (size_t)(b * Hh + h) * Ss * HD;
    const bf16* Vtbase = Vt + (size_t)(b * Hh + h) * HD * Ss;     // [d][s]
    const float* Abase = alibi + ((size_t)h * Ss + qt * 64) * Ss; // [q][s]
    const float* Mbase = mask + (size_t)b * Ss;

    // bf16 64x64 tile staging coords (2 chunks/wave, 8 rows x 128B each):
    int r8_0 = wave * 16 + (lane >> 3);
    int r8_1 = r8_0 + 8;
    int c8_0 = ((lane & 7) * 8) ^ ((r8_0 & 7) * 8);   // pre-swizzled source col
    int c8_1 = ((lane & 7) * 8) ^ ((r8_1 & 7) * 8);
    // fp32 64x64 tile staging coords (4 chunks/wave, 4 rows x 256B each):
    int ra[4], ca[4];
#pragma unroll
    for (int c = 0; c < 4; c++) {
        ra[c] = wave * 16 + c * 4 + (lane >> 4);
        ca[c] = ((lane & 15) * 4) ^ (((ra[c] >> 2) & 1) * 16);
    }
    const bf16* Kg0 = Kbase + (size_t)r8_0 * HD + c8_0;
    const bf16* Kg1 = Kbase + (size_t)r8_1 * HD + c8_1;
    const bf16* Vg0 = Vtbase + (size_t)r8_0 * Ss + c8_0;
    const bf16* Vg1 = Vtbase + (size_t)r8_1 * Ss + c8_1;
    const float* Ag0 = Abase + (size_t)ra[0] * Ss + ca[0];
    const float* Ag1 = Abase + (size_t)ra[1] * Ss + ca[1];
    const float* Ag2 = Abase + (size_t)ra[2] * Ss + ca[2];
    const float* Ag3 = Abase + (size_t)ra[3] * Ss + ca[3];

    // ---- prologue: everything via gload_lds, one barrier ----
    GL(Qbase + (size_t)r8_0 * HD + c8_0, &QPs[wave * 1024]);
    GL(Qbase + (size_t)r8_1 * HD + c8_1, &QPs[wave * 1024 + 512]);
    GL(Mbase + wave * 512 + lane * 4,        &Ms[wave * 512]);
    GL(Mbase + wave * 512 + 256 + lane * 4,  &Ms[wave * 512 + 256]);
    // tile 0
    GL(Kg0, &Ks[0][wave * 1024]);
    GL(Kg1, &Ks[0][wave * 1024 + 512]);
    GL(Vg0, &Vts[0][wave * 1024]);
    GL(Vg1, &Vts[0][wave * 1024 + 512]);
    GL(Ag0, &Als[0][wave * 1024]);
    GL(Ag1, &Als[0][wave * 1024 + 256]);
    GL(Ag2, &Als[0][wave * 1024 + 512]);
    GL(Ag3, &Als[0][wave * 1024 + 768]);
    __syncthreads();

    int qrow = wave * 16 + lane15;
    bf16x8 qf0 = *(const bf16x8*)(&QPs[qrow * 64 + ((quad * 8) ^ ((qrow & 7) * 8))]);
    bf16x8 qf1 = *(const bf16x8*)(&QPs[qrow * 64 + ((32 + quad * 8) ^ ((qrow & 7) * 8))]);

    float m_i[4], l_i[4];
    f32x4 O[4] = {};
#pragma unroll
    for (int r = 0; r < 4; r++) { m_i[r] = -1e30f; l_i[r] = 0.f; }

    const float scale = 0.125f;  // HD^-0.5

    int cur = 0;
    for (int kt = 0; kt < Ss; kt += KVB) {
        int nxt = cur ^ 1;
        // stage tile t+1 (in flight across the whole compute phase; drained at barrier)
        if (kt + KVB < Ss) {
            int kn = kt + KVB;
            GL(Kg0 + (size_t)kn * HD, &Ks[nxt][wave * 1024]);
            GL(Kg1 + (size_t)kn * HD, &Ks[nxt][wave * 1024 + 512]);
            GL(Vg0 + kn, &Vts[nxt][wave * 1024]);
            GL(Vg1 + kn, &Vts[nxt][wave * 1024 + 512]);
            GL(Ag0 + kn, &Als[nxt][wave * 1024]);
            GL(Ag1 + kn, &Als[nxt][wave * 1024 + 256]);
            GL(Ag2 + kn, &Als[nxt][wave * 1024 + 512]);
            GL(Ag3 + kn, &Als[nxt][wave * 1024 + 768]);
        }

        // QK^T from LDS
        f32x4 sc[4];
        f32x4 z = {0.f, 0.f, 0.f, 0.f};
#pragma unroll
        for (int j = 0; j < 4; j++) {
            int krow = j * 16 + lane15;
            bf16x8 kf0 = *(const bf16x8*)(&Ks[cur][krow * 64 + ((quad * 8) ^ ((krow & 7) * 8))]);
            bf16x8 kf1 = *(const bf16x8*)(&Ks[cur][krow * 64 + ((32 + quad * 8) ^ ((krow & 7) * 8))]);
            f32x4 s = __builtin_amdgcn_mfma_f32_16x16x32_bf16(qf0, kf0, z, 0, 0, 0);
            s = __builtin_amdgcn_mfma_f32_16x16x32_bf16(qf1, kf1, s, 0, 0, 0);
            sc[j] = s;
        }
        // scores: alibi + mask from LDS
#pragma unroll
        for (int j = 0; j < 4; j++) {
            int col = j * 16 + lane15;
            float mk = Ms[kt + col];
#pragma unroll
            for (int r = 0; r < 4; r++) {
                int arow = wave * 16 + quad * 4 + r;
                float al = Als[cur][arow * 64 + (col ^ (((arow >> 2) & 1) * 16))];
                sc[j][r] = sc[j][r] * scale + al + mk;
            }
        }
        // online softmax
        float alpha[4];
#pragma unroll
        for (int r = 0; r < 4; r++) {
            float v = fmaxf(fmaxf(sc[0][r], sc[1][r]), fmaxf(sc[2][r], sc[3][r]));
#pragma unroll
            for (int d = 1; d < 16; d <<= 1) v = fmaxf(v, __shfl_xor(v, d, 64));
            float mnew = fmaxf(m_i[r], v);
            alpha[r] = __expf(m_i[r] - mnew);
            m_i[r] = mnew;
        }
        float rs[4] = {0.f, 0.f, 0.f, 0.f};
#pragma unroll
        for (int j = 0; j < 4; j++)
#pragma unroll
            for (int r = 0; r < 4; r++) {
                float p = __expf(sc[j][r] - m_i[r]);
                sc[j][r] = p;
                rs[r] += p;
            }
#pragma unroll
        for (int r = 0; r < 4; r++) {
            float v = rs[r];
#pragma unroll
            for (int d = 1; d < 16; d <<= 1) v += __shfl_xor(v, d, 64);
            l_i[r] = l_i[r] * alpha[r] + v;
        }
        // P -> LDS (rows are wave-private: LDS drain only, no barrier)
#pragma unroll
        for (int j = 0; j < 4; j++)
#pragma unroll
            for (int r = 0; r < 4; r++) {
                int row = wave * 16 + quad * 4 + r;
                QPs[row * 64 + ((j * 16 + lane15) ^ ((row & 7) * 8))] = (bf16)sc[j][r];
            }
        asm volatile("s_waitcnt lgkmcnt(0)" ::: "memory");
        int prow = wave * 16 + lane15;
        bf16x8 pf0 = *(const bf16x8*)(&QPs[prow * 64 + ((quad * 8) ^ ((prow & 7) * 8))]);
        bf16x8 pf1 = *(const bf16x8*)(&QPs[prow * 64 + ((32 + quad * 8) ^ ((prow & 7) * 8))]);
        // PV: B-operand = Vt[d][k-packed] straight from LDS
#pragma unroll
        for (int jd = 0; jd < 4; jd++) {
            int vrow = jd * 16 + lane15;
#pragma unroll
            for (int r = 0; r < 4; r++) O[jd][r] *= alpha[r];
            bf16x8 vf0 = *(const bf16x8*)(&Vts[cur][vrow * 64 + ((quad * 8) ^ ((vrow & 7) * 8))]);
            bf16x8 vf1 = *(const bf16x8*)(&Vts[cur][vrow * 64 + ((32 + quad * 8) ^ ((vrow & 7) * 8))]);
            O[jd] = __builtin_amdgcn_mfma_f32_16x16x32_bf16(pf0, vf0, O[jd], 0, 0, 0);
            O[jd] = __builtin_amdgcn_mfma_f32_16x16x32_bf16(pf1, vf1, O[jd], 0, 0, 0);
        }
        __syncthreads();   // drains stage(t+1) vmcnt + guards buffer swap
        cur = nxt;
    }

#pragma unroll
    for (int jd = 0; jd < 4; jd++) {
        int d = jd * 16 + lane15;
#pragma unroll
        for (int r = 0; r < 4; r++) {
            int qg = qt * 64 + wave * 16 + quad * 4 + r;
            float v = O[jd][r] / l_i[r];
            outattn[(((size_t)b * Ss + qg) * Hh + h) * HD + d] = (bf16)v;
        }
    }
}

// ---------------- residual + layernorm ----------------
__global__ void ln_kernel(const float* __restrict__ hidden, const bf16* __restrict__ Y,
                          const float* __restrict__ gamma, const float* __restrict__ beta,
                          float* __restrict__ out) {
    int row = blockIdx.x;
    int tid = threadIdx.x, wave = tid >> 6, lane = tid & 63;
    float x[4];
    float s = 0.f, q = 0.f;
#pragma unroll
    for (int e = 0; e < 4; e++) {
        int col = e * 256 + tid;
        x[e] = hidden[(size_t)row * Dd + col] + (float)Y[(size_t)row * Dd + col];
        s += x[e];
        q += x[e] * x[e];
    }
#pragma unroll
    for (int d = 1; d < 64; d <<= 1) { s += __shfl_xor(s, d, 64); q += __shfl_xor(q, d, 64); }
    __shared__ float sm[4], sq[4];
    if (lane == 0) { sm[wave] = s; sq[wave] = q; }
    __syncthreads();
    float tot = sm[0] + sm[1] + sm[2] + sm[3];
    float totq = sq[0] + sq[1] + sq[2] + sq[3];
    float mu = tot * (1.f / 1024.f);
    float var = totq * (1.f / 1024.f) - mu * mu;
    float rstd = rsqrtf(var + 1e-12f);
#pragma unroll
    for (int e = 0; e < 4; e++) {
        int col = e * 256 + tid;
        out[(size_t)row * Dd + col] = (x[e] - mu) * rstd * gamma[col] + beta[col];
    }
}

// ---------------- launch ----------------
extern "C" void kernel_launch(void* const* d_in, const int* in_sizes, int n_in,
                              void* d_out, int out_size, void* d_ws, size_t ws_size,
                              hipStream_t stream) {
    const float* hidden = (const float*)d_in[0];
    const float* amask  = (const float*)d_in[1];
    const float* alibi  = (const float*)d_in[2];
    const float* Wq = (const float*)d_in[3];
    const float* bq = (const float*)d_in[4];
    const float* Wk = (const float*)d_in[5];
    const float* bk = (const float*)d_in[6];
    const float* Wv = (const float*)d_in[7];
    const float* bv = (const float*)d_in[8];
    const float* Wo = (const float*)d_in[9];
    const float* bo = (const float*)d_in[10];
    const float* ln_g = (const float*)d_in[11];
    const float* ln_b = (const float*)d_in[12];
    float* out = (float*)d_out;

    char* w = (char*)d_ws;
    bf16* Xb   = (bf16*)(w);                       // 4096x1024; reused as Vt after QKV GEMM
    bf16* WqT  = (bf16*)(w + 8388608);             // [WqT;WkT;WvT] contiguous 3072x1024
    bf16* WkT  = (bf16*)(w + 10485760);
    bf16* WvT  = (bf16*)(w + 12582912);
    bf16* WoT  = (bf16*)(w + 14680064);
    bf16* Qw   = (bf16*)(w + 16777216);            // [B,H,S,HD]
    bf16* Kw   = (bf16*)(w + 25165824);
    bf16* Vw   = (bf16*)(w + 33554432);
    bf16* Attn = (bf16*)(w + 41943040);            // [B,S,H,HD] = [4096,1024]
    bf16* Yw   = (bf16*)(w + 50331648);
    bf16* Vtw  = Xb;                               // [B,H,HD,S] (Xb dead after QKV GEMM)

    cvt_f32_bf16<<<4096, 256, 0, stream>>>(hidden, Xb, Mm * Dd / 4);
    wtrans<<<dim3(16, 16, 4), 256, 0, stream>>>(Wq, Wk, Wv, Wo, WqT, WkT, WvT, WoT);

    gemm_bt<128><<<dim3(32, 24), 256, 0, stream>>>(Xb, WqT, bq, bk, bv, Qw, Kw, Vw, 1);

    vtrans<<<dim3(32, 32), 256, 0, stream>>>(Vw, Vtw);

    attn_kernel<<<1024, 256, 0, stream>>>(Qw, Kw, Vtw, alibi, amask, Attn);

    gemm_bt<64><<<dim3(64, 8), 256, 0, stream>>>(Attn, WoT, bo, nullptr, nullptr, Yw, nullptr, nullptr, 0);

    ln_kernel<<<4096, 256, 0, stream>>>(hidden, Yw, ln_g, ln_b, out);
}

// Round 5
// 535.890 us; speedup vs baseline: 1.3693x; 1.0593x over previous
//
#include <hip/hip_runtime.h>

#define Bb 2
#define Ss 2048
#define Dd 1024
#define Hh 16
#define HD 64
#define Mm (Bb*Ss)   // 4096
#define KVB 64

typedef __bf16 bf16;
typedef __bf16 bf16x8 __attribute__((ext_vector_type(8)));
typedef __bf16 bf16x4 __attribute__((ext_vector_type(4)));
typedef float f32x4 __attribute__((ext_vector_type(4)));

// async global->LDS, 16B per lane; LDS dest must be wave-uniform base (+lane*16 implicit)
#define GL(gp, lp) __builtin_amdgcn_global_load_lds( \
        (const __attribute__((address_space(1))) unsigned int*)(gp), \
        (__attribute__((address_space(3))) unsigned int*)(lp), 16, 0, 0)

// ---------------- prep: fp32 -> bf16 cast ----------------
__global__ void cvt_f32_bf16(const float* __restrict__ in, bf16* __restrict__ out, int n4) {
    int i = blockIdx.x * blockDim.x + threadIdx.x;
    if (i < n4) {
        float4 v = *(const float4*)(in + i * 4);
        out[i*4+0] = (bf16)v.x; out[i*4+1] = (bf16)v.y;
        out[i*4+2] = (bf16)v.z; out[i*4+3] = (bf16)v.w;
    }
}

// ---------------- prep: W [K,N] fp32 -> Wt [N,K] bf16 ----------------
__global__ void wtrans(const float* __restrict__ W0, const float* __restrict__ W1,
                       const float* __restrict__ W2, const float* __restrict__ W3,
                       bf16* __restrict__ O0, bf16* __restrict__ O1,
                       bf16* __restrict__ O2, bf16* __restrict__ O3) {
    const float* W = (blockIdx.z == 0) ? W0 : (blockIdx.z == 1) ? W1 : (blockIdx.z == 2) ? W2 : W3;
    bf16* O = (blockIdx.z == 0) ? O0 : (blockIdx.z == 1) ? O1 : (blockIdx.z == 2) ? O2 : O3;
    __shared__ bf16 t[64][65];
    int k0 = blockIdx.x * 64, n0 = blockIdx.y * 64;
    for (int c = threadIdx.x; c < 4096; c += 256) {
        int r = c >> 6, cc = c & 63;
        t[r][cc] = (bf16)W[(k0 + r) * Dd + n0 + cc];
    }
    __syncthreads();
    for (int c = threadIdx.x; c < 4096; c += 256) {
        int r = c >> 6, cc = c & 63;
        O[(n0 + r) * Dd + k0 + cc] = t[cc][r];
    }
}

// ---------------- prep: V [BH,S,HD] -> Vt [BH,HD,S] ----------------
__global__ void vtrans(const bf16* __restrict__ in, bf16* __restrict__ out) {
    __shared__ bf16 t[64][72];
    int s0 = blockIdx.x * 64, bh = blockIdx.y;
    int tid = threadIdx.x;
    int r = tid >> 3, c = (tid & 7) * 8;
    const bf16* ib = in + ((size_t)bh * Ss + s0) * HD;
    bf16x8 v0 = *(const bf16x8*)(&ib[(size_t)r * HD + c]);
    bf16x8 v1 = *(const bf16x8*)(&ib[(size_t)(r + 32) * HD + c]);
    *(bf16x8*)(&t[r][c]) = v0;
    *(bf16x8*)(&t[r + 32][c]) = v1;
    __syncthreads();
    int d0 = tid >> 3, d1 = d0 + 32, sc2 = (tid & 7) * 8;
    bf16x8 o0, o1;
#pragma unroll
    for (int e = 0; e < 8; e++) { o0[e] = t[sc2 + e][d0]; o1[e] = t[sc2 + e][d1]; }
    *(bf16x8*)(&out[((size_t)(bh * HD + d0)) * Ss + s0 + sc2]) = o0;
    *(bf16x8*)(&out[((size_t)(bh * HD + d1)) * Ss + s0 + sc2]) = o1;
}

// ---------------- GEMM: C[M,N] = A[M,K] * Bt[N,K]^T + bias ----------------
// BM x 128 tile, BK=32, 4 waves. Double-buffered LDS, stage(t+1) before compute(t),
// one barrier per K-step.
template<int BM>
__global__ __launch_bounds__(256, (BM == 64) ? 4 : 3)
void gemm_bt(const bf16* __restrict__ A, const bf16* __restrict__ Bt,
             const float* __restrict__ b0, const float* __restrict__ b1, const float* __restrict__ b2,
             bf16* __restrict__ o0, bf16* __restrict__ o1, bf16* __restrict__ o2, int mode) {
    const int K = 1024;
    constexpr int MI = BM / 32;
    __shared__ __align__(16) bf16 As[2][BM * 32];
    __shared__ __align__(16) bf16 Bs[2][128 * 32];
    int tid = threadIdx.x;
    int wave = tid >> 6, lane = tid & 63;
    int lane15 = lane & 15, quad = lane >> 4;
    int wm = (wave >> 1) * (BM / 2), wn = (wave & 1) * 64;
    int m0 = blockIdx.x * BM, n0 = blockIdx.y * 128;
    int lrow = lane >> 2, lcol = (lane & 3) * 8;
    const bf16* Ag = &A[(size_t)(m0 + wave * 16 + lrow) * K + lcol];
    const bf16* Bg = &Bt[(size_t)(n0 + wave * 16 + lrow) * K + lcol];

    f32x4 acc[MI][4] = {};

#define STAGE(buf, kt) do { \
        bf16* Asw = &As[buf][wave * 16 * 32]; \
        bf16* Bsw = &Bs[buf][wave * 16 * 32]; \
        GL(Ag + (kt), Asw); \
        if constexpr (BM == 128) GL(Ag + 64 * K + (kt), Asw + 64 * 32); \
        GL(Bg + (kt), Bsw); \
        GL(Bg + 64 * K + (kt), Bsw + 64 * 32); \
    } while (0)

    STAGE(0, 0);
    __syncthreads();
    int cur = 0;
    for (int kt = 0; kt < K; kt += 32) {
        if (kt + 32 < K) STAGE(cur ^ 1, kt + 32);
        bf16x8 af[MI], bfr[4];
#pragma unroll
        for (int i = 0; i < MI; i++) af[i] = *(const bf16x8*)(&As[cur][(wm + i * 16 + lane15) * 32 + quad * 8]);
#pragma unroll
        for (int j = 0; j < 4; j++) bfr[j] = *(const bf16x8*)(&Bs[cur][(wn + j * 16 + lane15) * 32 + quad * 8]);
#pragma unroll
        for (int i = 0; i < MI; i++)
#pragma unroll
            for (int j = 0; j < 4; j++)
                acc[i][j] = __builtin_amdgcn_mfma_f32_16x16x32_bf16(af[i], bfr[j], acc[i][j], 0, 0, 0);
        __syncthreads();
        cur ^= 1;
    }
#undef STAGE

#pragma unroll
    for (int i = 0; i < MI; i++) {
        int mbase = m0 + wm + i * 16 + quad * 4;
#pragma unroll
        for (int j = 0; j < 4; j++) {
            int n = n0 + wn + j * 16 + lane15;
            if (mode == 0) {
                float bv = b0[n];
#pragma unroll
                for (int r = 0; r < 4; r++)
                    o0[(size_t)(mbase + r) * 1024 + n] = (bf16)(acc[i][j][r] + bv);
            } else {
                int which = n >> 10, nn = n & 1023;
                const float* bp = (which == 0) ? b0 : (which == 1) ? b1 : b2;
                bf16* op = (which == 0) ? o0 : (which == 1) ? o1 : o2;
                float bv = bp[nn];
                int hh = nn >> 6, hd = nn & 63;
#pragma unroll
                for (int r = 0; r < 4; r++) {
                    int m = mbase + r;
                    int bb = m >> 11, s = m & 2047;
                    op[(((size_t)(bb * Hh + hh) * Ss + s) * HD) + hd] = (bf16)(acc[i][j][r] + bv);
                }
            }
        }
    }
}

// ---------------- flash attention ----------------
// 1024 blocks 1-D, 256 threads (4 waves). Twin decode: b=(id>>3)&1 -> b=0/b=1 blocks
// with the same (qt,h) are 8 apart (same XCD, adjacent launch) -> alibi L2 reuse.
// K and Vt stream via global_load_lds (pre-swizzled source, linear dest), double-
// buffered, staged one tile ahead; alibi+mask go DIRECT to registers, issued BEFORE
// the stage so the compiler's alibi wait is a counted vmcnt that leaves K/V in flight.
// LDS = 40960 B exactly -> 4 blocks/CU -> all 1024 blocks co-resident (one batch).
// VGPR budget ~112 under the 128 cap of __launch_bounds__(256,4): no spill.
__global__ __launch_bounds__(256, 4)
void attn_kernel(const bf16* __restrict__ Q, const bf16* __restrict__ Kk, const bf16* __restrict__ Vt,
                 const float* __restrict__ alibi, const float* __restrict__ mask,
                 bf16* __restrict__ outattn) {
    int hwid = blockIdx.x;
    int b = (hwid >> 3) & 1;
    int pid = ((hwid >> 4) << 3) | (hwid & 7);
    int qt = pid & 31, h = pid >> 5;

    __shared__ __align__(16) bf16 Ks[2][64 * 64];
    __shared__ __align__(16) bf16 Vts[2][64 * 64];
    __shared__ __align__(16) bf16 QPs[64 * 64];

    int tid = threadIdx.x, wave = tid >> 6, lane = tid & 63;
    int lane15 = lane & 15, quad = lane >> 4;

    const bf16* Qbase = Q + ((size_t)(b * Hh + h) * Ss + qt * 64) * HD;
    const bf16* Kbase = Kk + (size_t)(b * Hh + h) * Ss * HD;
    const bf16* Vtbase = Vt + (size_t)(b * Hh + h) * HD * Ss;     // [d][s]
    const float* alibi_q = alibi + ((size_t)h * Ss + qt * 64 + wave * 16 + quad * 4) * Ss;
    const float* Mbase = mask + (size_t)b * Ss;

    // bf16 64x64 tile staging coords (2 chunks/wave, 8 rows x 128B each):
    int r8_0 = wave * 16 + (lane >> 3);
    int r8_1 = r8_0 + 8;
    int c8_0 = ((lane & 7) * 8) ^ ((r8_0 & 7) * 8);   // pre-swizzled source col
    int c8_1 = ((lane & 7) * 8) ^ ((r8_1 & 7) * 8);
    const bf16* Kg0 = Kbase + (size_t)r8_0 * HD + c8_0;
    const bf16* Kg1 = Kbase + (size_t)r8_1 * HD + c8_1;
    const bf16* Vg0 = Vtbase + (size_t)r8_0 * Ss + c8_0;
    const bf16* Vg1 = Vtbase + (size_t)r8_1 * Ss + c8_1;

    // ---- prologue ----
    GL(Qbase + (size_t)r8_0 * HD + c8_0, &QPs[wave * 1024]);
    GL(Qbase + (size_t)r8_1 * HD + c8_1, &QPs[wave * 1024 + 512]);
    GL(Kg0, &Ks[0][wave * 1024]);
    GL(Kg1, &Ks[0][wave * 1024 + 512]);
    GL(Vg0, &Vts[0][wave * 1024]);
    GL(Vg1, &Vts[0][wave * 1024 + 512]);
    __syncthreads();

    int qrow = wave * 16 + lane15;
    bf16x8 qf0 = *(const bf16x8*)(&QPs[qrow * 64 + ((quad * 8) ^ ((qrow & 7) * 8))]);
    bf16x8 qf1 = *(const bf16x8*)(&QPs[qrow * 64 + ((32 + quad * 8) ^ ((qrow & 7) * 8))]);

    float m_i[4], l_i[4];
    f32x4 O[4] = {};
#pragma unroll
    for (int r = 0; r < 4; r++) { m_i[r] = -1e30f; l_i[r] = 0.f; }

    const float scale = 0.125f;  // HD^-0.5

    int cur = 0;
    for (int kt = 0; kt < Ss; kt += KVB) {
        int nxt = cur ^ 1;
        // (A) alibi + mask for THIS tile -> registers. Issued FIRST (oldest vmcnt):
        // the wait for these is a counted vmcnt that leaves the (B) stage in flight.
        float al[4][4], mk[4];
#pragma unroll
        for (int j = 0; j < 4; j++) {
#pragma unroll
            for (int r = 0; r < 4; r++)
                al[j][r] = alibi_q[(size_t)r * Ss + kt + j * 16 + lane15];
            mk[j] = Mbase[kt + j * 16 + lane15];
        }
        // (B) stage tile t+1 (drained only at the end-of-tile barrier)
        if (kt + KVB < Ss) {
            int kn = kt + KVB;
            GL(Kg0 + (size_t)kn * HD, &Ks[nxt][wave * 1024]);
            GL(Kg1 + (size_t)kn * HD, &Ks[nxt][wave * 1024 + 512]);
            GL(Vg0 + kn, &Vts[nxt][wave * 1024]);
            GL(Vg1 + kn, &Vts[nxt][wave * 1024 + 512]);
        }

        // (C) QK^T from LDS
        f32x4 sc[4];
        f32x4 z = {0.f, 0.f, 0.f, 0.f};
#pragma unroll
        for (int j = 0; j < 4; j++) {
            int krow = j * 16 + lane15;
            bf16x8 kf0 = *(const bf16x8*)(&Ks[cur][krow * 64 + ((quad * 8) ^ ((krow & 7) * 8))]);
            bf16x8 kf1 = *(const bf16x8*)(&Ks[cur][krow * 64 + ((32 + quad * 8) ^ ((krow & 7) * 8))]);
            f32x4 s = __builtin_amdgcn_mfma_f32_16x16x32_bf16(qf0, kf0, z, 0, 0, 0);
            s = __builtin_amdgcn_mfma_f32_16x16x32_bf16(qf1, kf1, s, 0, 0, 0);
            sc[j] = s;
        }
        // (D) scores
#pragma unroll
        for (int j = 0; j < 4; j++)
#pragma unroll
            for (int r = 0; r < 4; r++)
                sc[j][r] = sc[j][r] * scale + al[j][r] + mk[j];
        // (E) online softmax
        float alpha[4];
#pragma unroll
        for (int r = 0; r < 4; r++) {
            float v = fmaxf(fmaxf(sc[0][r], sc[1][r]), fmaxf(sc[2][r], sc[3][r]));
#pragma unroll
            for (int d = 1; d < 16; d <<= 1) v = fmaxf(v, __shfl_xor(v, d, 64));
            float mnew = fmaxf(m_i[r], v);
            alpha[r] = __expf(m_i[r] - mnew);
            m_i[r] = mnew;
        }
        float rs[4] = {0.f, 0.f, 0.f, 0.f};
#pragma unroll
        for (int j = 0; j < 4; j++)
#pragma unroll
            for (int r = 0; r < 4; r++) {
                float p = __expf(sc[j][r] - m_i[r]);
                sc[j][r] = p;
                rs[r] += p;
            }
#pragma unroll
        for (int r = 0; r < 4; r++) {
            float v = rs[r];
#pragma unroll
            for (int d = 1; d < 16; d <<= 1) v += __shfl_xor(v, d, 64);
            l_i[r] = l_i[r] * alpha[r] + v;
        }
        // (F) P -> LDS (rows are wave-private: LDS drain only, no barrier)
#pragma unroll
        for (int j = 0; j < 4; j++)
#pragma unroll
            for (int r = 0; r < 4; r++) {
                int row = wave * 16 + quad * 4 + r;
                QPs[row * 64 + ((j * 16 + lane15) ^ ((row & 7) * 8))] = (bf16)sc[j][r];
            }
        asm volatile("s_waitcnt lgkmcnt(0)" ::: "memory");
        int prow = wave * 16 + lane15;
        bf16x8 pf0 = *(const bf16x8*)(&QPs[prow * 64 + ((quad * 8) ^ ((prow & 7) * 8))]);
        bf16x8 pf1 = *(const bf16x8*)(&QPs[prow * 64 + ((32 + quad * 8) ^ ((prow & 7) * 8))]);
        // (G) PV
#pragma unroll
        for (int jd = 0; jd < 4; jd++) {
            int vrow = jd * 16 + lane15;
#pragma unroll
            for (int r = 0; r < 4; r++) O[jd][r] *= alpha[r];
            bf16x8 vf0 = *(const bf16x8*)(&Vts[cur][vrow * 64 + ((quad * 8) ^ ((vrow & 7) * 8))]);
            bf16x8 vf1 = *(const bf16x8*)(&Vts[cur][vrow * 64 + ((32 + quad * 8) ^ ((vrow & 7) * 8))]);
            O[jd] = __builtin_amdgcn_mfma_f32_16x16x32_bf16(pf0, vf0, O[jd], 0, 0, 0);
            O[jd] = __builtin_amdgcn_mfma_f32_16x16x32_bf16(pf1, vf1, O[jd], 0, 0, 0);
        }
        __syncthreads();   // drains stage(t+1) vmcnt + guards buffer swap
        cur = nxt;
    }

#pragma unroll
    for (int jd = 0; jd < 4; jd++) {
        int d = jd * 16 + lane15;
#pragma unroll
        for (int r = 0; r < 4; r++) {
            int qg = qt * 64 + wave * 16 + quad * 4 + r;
            float v = O[jd][r] / l_i[r];
            outattn[(((size_t)b * Ss + qg) * Hh + h) * HD + d] = (bf16)v;
        }
    }
}

// ---------------- residual + layernorm (vectorized) ----------------
__global__ void ln_kernel(const float* __restrict__ hidden, const bf16* __restrict__ Y,
                          const float* __restrict__ gamma, const float* __restrict__ beta,
                          float* __restrict__ out) {
    int row = blockIdx.x;
    int tid = threadIdx.x, wave = tid >> 6, lane = tid & 63;
    float4 hv = *(const float4*)(&hidden[(size_t)row * Dd + tid * 4]);
    bf16x4 yv = *(const bf16x4*)(&Y[(size_t)row * Dd + tid * 4]);
    float x[4] = {hv.x + (float)yv[0], hv.y + (float)yv[1],
                  hv.z + (float)yv[2], hv.w + (float)yv[3]};
    float s = 0.f, q = 0.f;
#pragma unroll
    for (int e = 0; e < 4; e++) { s += x[e]; q += x[e] * x[e]; }
#pragma unroll
    for (int d = 1; d < 64; d <<= 1) { s += __shfl_xor(s, d, 64); q += __shfl_xor(q, d, 64); }
    __shared__ float sm[4], sq[4];
    if (lane == 0) { sm[wave] = s; sq[wave] = q; }
    __syncthreads();
    float tot = sm[0] + sm[1] + sm[2] + sm[3];
    float totq = sq[0] + sq[1] + sq[2] + sq[3];
    float mu = tot * (1.f / 1024.f);
    float var = totq * (1.f / 1024.f) - mu * mu;
    float rstd = rsqrtf(var + 1e-12f);
    float4 gv = *(const float4*)(&gamma[tid * 4]);
    float4 bv = *(const float4*)(&beta[tid * 4]);
    float4 ov;
    ov.x = (x[0] - mu) * rstd * gv.x + bv.x;
    ov.y = (x[1] - mu) * rstd * gv.y + bv.y;
    ov.z = (x[2] - mu) * rstd * gv.z + bv.z;
    ov.w = (x[3] - mu) * rstd * gv.w + bv.w;
    *(float4*)(&out[(size_t)row * Dd + tid * 4]) = ov;
}

// ---------------- launch ----------------
extern "C" void kernel_launch(void* const* d_in, const int* in_sizes, int n_in,
                              void* d_out, int out_size, void* d_ws, size_t ws_size,
                              hipStream_t stream) {
    const float* hidden = (const float*)d_in[0];
    const float* amask  = (const float*)d_in[1];
    const float* alibi  = (const float*)d_in[2];
    const float* Wq = (const float*)d_in[3];
    const float* bq = (const float*)d_in[4];
    const float* Wk = (const float*)d_in[5];
    const float* bk = (const float*)d_in[6];
    const float* Wv = (const float*)d_in[7];
    const float* bv = (const float*)d_in[8];
    const float* Wo = (const float*)d_in[9];
    const float* bo = (const float*)d_in[10];
    const float* ln_g = (const float*)d_in[11];
    const float* ln_b = (const float*)d_in[12];
    float* out = (float*)d_out;

    char* w = (char*)d_ws;
    bf16* Xb   = (bf16*)(w);                       // 4096x1024; reused as Vt after QKV GEMM
    bf16* WqT  = (bf16*)(w + 8388608);             // [WqT;WkT;WvT] contiguous 3072x1024
    bf16* WkT  = (bf16*)(w + 10485760);
    bf16* WvT  = (bf16*)(w + 12582912);
    bf16* WoT  = (bf16*)(w + 14680064);
    bf16* Qw   = (bf16*)(w + 16777216);            // [B,H,S,HD]
    bf16* Kw   = (bf16*)(w + 25165824);
    bf16* Vw   = (bf16*)(w + 33554432);
    bf16* Attn = (bf16*)(w + 41943040);            // [B,S,H,HD] = [4096,1024]
    bf16* Yw   = (bf16*)(w + 50331648);
    bf16* Vtw  = Xb;                               // [B,H,HD,S] (Xb dead after QKV GEMM)

    cvt_f32_bf16<<<4096, 256, 0, stream>>>(hidden, Xb, Mm * Dd / 4);
    wtrans<<<dim3(16, 16, 4), 256, 0, stream>>>(Wq, Wk, Wv, Wo, WqT, WkT, WvT, WoT);

    gemm_bt<128><<<dim3(32, 24), 256, 0, stream>>>(Xb, WqT, bq, bk, bv, Qw, Kw, Vw, 1);

    vtrans<<<dim3(32, 32), 256, 0, stream>>>(Vw, Vtw);

    attn_kernel<<<1024, 256, 0, stream>>>(Qw, Kw, Vtw, alibi, amask, Attn);

    gemm_bt<64><<<dim3(64, 8), 256, 0, stream>>>(Attn, WoT, bo, nullptr, nullptr, Yw, nullptr, nullptr, 0);

    ln_kernel<<<4096, 256, 0, stream>>>(hidden, Yw, ln_g, ln_b, out);
}